// Round 2
// 353.923 us; speedup vs baseline: 1.6667x; 1.6667x over previous
//
#include <hip/hip_runtime.h>
#include <hip/hip_bf16.h>
#include <stdint.h>

// GeometricGNN on MI355X. R=2048, APR=8, H=512, HEADS=4, HD=128, SD=28.
// Round 19b: attention rewritten on MFMA (mfma_f32_16x16x32_bf16).
//  - qkv stored bf16 always; V stored TRANSPOSED per head ([4][128][2048]).
//  - attn_mfma: 4 waves/block, each wave owns a private K/Vt LDS tile and a
//    disjoint kt range (no barriers in the main loop). Q-fragments in regs.
//    QK^T -> exp/den/pos on C-layout -> P as bf16 via per-wave Ash -> PV.
//    XOR swizzle (byte ^= (row&7)<<4) on K/Vt fragment reads.
//  - cross-wave reduction of O / den / pos via LDS after the loop.
// Everything else (gather, qkv GEMM core, wo, final_ln) R17/R18-identical.
// (R19 fix: renamed ushort4 -> us4; HIP headers own the name ushort4.)

#define R_ 2048
#define APR_ 8
#define H_ 512
#define HEADS_ 4
#define HD_ 128
#define FA_LD 544

typedef __attribute__((ext_vector_type(4))) float f32x4;
typedef __attribute__((ext_vector_type(4))) unsigned int u32x4;
typedef __attribute__((ext_vector_type(4))) unsigned short us4;
typedef __bf16 bf16x8 __attribute__((ext_vector_type(8)));

static __device__ __forceinline__ float bf2f(unsigned short u) {
    union { unsigned int i; float f; } c; c.i = ((unsigned int)u) << 16; return c.f;
}
static __device__ __forceinline__ unsigned short f2bf(float f) {
    union { float f; unsigned int i; } c; c.f = f;
    unsigned int r = c.i + 0x7fffu + ((c.i >> 16) & 1u);   // RNE
    return (unsigned short)(r >> 16);
}
// flag-aware, sanitized load of logical element i of a float input array
static __device__ __forceinline__ float loadf(const void* p, size_t i, bool f32) {
    float v = f32 ? ((const float*)p)[i] : bf2f(((const unsigned short*)p)[i]);
    return (v == v && fabsf(v) < 1e30f) ? v : 0.f;
}

// ---------------------------------------------------------------- diag
__global__ void diag(unsigned short* out, float val) {
    if (threadIdx.x == 0 && blockIdx.x == 0) out[0] = f2bf(val);
}

// ---------------------------------------------------------------- dtype detect (d_in[0])
__global__ void detect_dtype(const unsigned short* __restrict__ nf, int* flag) {
    __shared__ int bad;
    if (threadIdx.x == 0) bad = 0;
    __syncthreads();
    int cnt = 0;
    for (int i = threadIdx.x; i < 8192; i += 256) {
        unsigned e = (nf[i] >> 7) & 0xFFu;
        if (e >= 0xC0u) cnt++;
    }
    atomicAdd(&bad, cnt);
    __syncthreads();
    if (threadIdx.x == 0) *flag = (bad > 16) ? 1 : 0;
}

// ---------------------------------------------------------------- gather + frames (R17 verbatim)
__global__ void gather_frames(const void* __restrict__ pos,
                              const int* __restrict__ atype,
                              const int* __restrict__ flag,
                              int* __restrict__ cai, float* __restrict__ ca,
                              float* __restrict__ cb, float* __restrict__ fr,
                              float* __restrict__ maskf)
{
    int r = blockIdx.x * blockDim.x + threadIdx.x;
    if (r >= R_) return;
    bool f32 = *flag != 0;
    int base = r * APR_;
    float caP[3] = {0,0,0}, cbP[3] = {0,0,0};
    int idx = base; bool h0=false, h1=false, h2=false;
    for (int a = 0; a < APR_; a++) {
        int t = atype[base + a];
        if (t == 0) h0 = true;
        if (t == 2) h2 = true;
        if (t == 1) { h1 = true; idx = base + a;
            for (int j = 0; j < 3; j++) caP[j] += loadf(pos, (size_t)(base+a)*3 + j, f32); }
        if (t == 4) {
            for (int j = 0; j < 3; j++) cbP[j] += loadf(pos, (size_t)(base+a)*3 + j, f32); }
    }
    float s = fabsf(cbP[0]) + fabsf(cbP[1]) + fabsf(cbP[2]);
    if (s < 1e-6f) { cbP[0]=caP[0]; cbP[1]=caP[1]; cbP[2]=caP[2]; }
    float e1[3] = { cbP[0]-caP[0], cbP[1]-caP[1], cbP[2]-caP[2] };
    float n1 = sqrtf(e1[0]*e1[0] + e1[1]*e1[1] + e1[2]*e1[2]);
    float e1u[3] = { e1[0], e1[1], e1[2] };
    if (n1 > 1e-6f) { float iv = 1.f / fmaxf(n1, 1e-6f); e1u[0]*=iv; e1u[1]*=iv; e1u[2]*=iv; }
    float e2a[3] = { e1u[1], -e1u[0], 0.f };
    float n2a = sqrtf(e2a[0]*e2a[0] + e2a[1]*e2a[1]);
    float e2b[3] = { -e1u[2], 0.f, e1u[0] };
    float n2b = sqrtf(e2b[0]*e2b[0] + e2b[2]*e2b[2]);
    bool useb = n2a < 1e-6f;
    float e2[3] = { useb?e2b[0]:e2a[0], useb?e2b[1]:e2a[1], useb?e2b[2]:e2a[2] };
    float n2 = useb ? n2b : n2a;
    float iv2 = 1.f / fmaxf(n2, 1e-6f);
    float e2u[3] = { e2[0]*iv2, e2[1]*iv2, e2[2]*iv2 };
    float e3[3] = { e1u[1]*e2u[2]-e1u[2]*e2u[1],
                    e1u[2]*e2u[0]-e1u[0]*e2u[2],
                    e1u[0]*e2u[1]-e1u[1]*e2u[0] };
    bool ok = (r < R_-1) && (n1 > 1e-6f) && (n2 > 1e-6f);
    float F[9];
    if (ok) { F[0]=e1u[0]; F[1]=e2u[0]; F[2]=e3[0];
              F[3]=e1u[1]; F[4]=e2u[1]; F[5]=e3[1];
              F[6]=e1u[2]; F[7]=e2u[2]; F[8]=e3[2]; }
    else    { F[0]=1;F[1]=0;F[2]=0; F[3]=0;F[4]=1;F[5]=0; F[6]=0;F[7]=0;F[8]=1; }
    cai[r] = idx;
    for (int j = 0; j < 3; j++) { ca[r*3+j] = caP[j]; cb[r*3+j] = cbP[j]; }
    for (int j = 0; j < 9; j++) fr[r*9+j] = F[j];
    maskf[r] = (h0 && h1 && h2) ? 1.f : 0.f;
}

// ---------------------------------------------------------------- QKV tiled GEMM (bf16 out; V transposed)
__global__ __launch_bounds__(256) void qkv_tile(
    const void* __restrict__ nf, const int* __restrict__ cai,
    const void* __restrict__ Wq, const void* __restrict__ Wk, const void* __restrict__ Wv,
    const void* __restrict__ bq, const void* __restrict__ bk, const void* __restrict__ bv,
    void* __restrict__ qf, void* __restrict__ kf, void* __restrict__ vtf,
    const int* __restrict__ flag)
{
    __shared__ __align__(16) float Xs[32][68];   // [k][m]
    __shared__ __align__(16) float Wsh[32][68];  // [k][n]
    __shared__ int cais[64];
    const int tid = threadIdx.x;
    const int mbase = blockIdx.x * 64;
    const int nblk  = blockIdx.y * 64;           // 0..1535
    const int mat   = nblk >> 9;
    const int ncol0 = nblk & 511;
    bool f32 = *flag != 0;
    const void* W = (mat==0) ? Wq : (mat==1) ? Wk : Wv;
    const int tm = tid >> 4, tn = tid & 15;
    float acc[4][4] = {};
    if (tid < 64) cais[tid] = cai[mbase + tid];
    for (int kt = 0; kt < 16; kt++) {
        const int k0 = kt * 32;
        __syncthreads();   // prior iter reads done; iter0: cais visible
        for (int i = tid; i < 64*32; i += 256) {
            int m = i >> 5, kk = i & 31;
            Xs[kk][m] = loadf(nf, (size_t)cais[m]*H_ + k0 + kk, f32);
        }
        for (int i = tid; i < 32*64; i += 256) {
            int kk = i >> 6, nn = i & 63;
            Wsh[kk][nn] = loadf(W, (size_t)(k0+kk)*H_ + ncol0 + nn, f32);
        }
        __syncthreads();
        for (int k = 0; k < 32; k++) {
            f32x4 a = *(const f32x4*)&Xs[k][tm*4];
            f32x4 b = *(const f32x4*)&Wsh[k][tn*4];
            #pragma unroll
            for (int i = 0; i < 4; i++)
                #pragma unroll
                for (int j = 0; j < 4; j++)
                    acc[i][j] += a[i] * b[j];
        }
    }
    const void* bias = (mat==0) ? bq : (mat==1) ? bk : bv;
    if (mat == 2) {
        // V transposed, bf16: vt[(h*128+dloc)*2048 + r] with col = h*128+dloc
        unsigned short* vt = (unsigned short*)vtf;
        #pragma unroll
        for (int j = 0; j < 4; j++) {
            int col = ncol0 + tn*4 + j;
            float bc = loadf(bias, col, f32);
            us4 pk;
            #pragma unroll
            for (int i = 0; i < 4; i++) pk[i] = f2bf(acc[i][j] + bc);
            *(us4*)(vt + (size_t)col*R_ + mbase + tm*4) = pk;
        }
    } else {
        unsigned short* dst = (unsigned short*)((mat==0) ? qf : kf);
        #pragma unroll
        for (int i = 0; i < 4; i++) {
            int m = mbase + tm*4 + i;
            #pragma unroll
            for (int j = 0; j < 4; j++) {
                int col = ncol0 + tn*4 + j;
                dst[(size_t)m*H_ + col] = f2bf(acc[i][j] + loadf(bias, col, f32));
            }
        }
    }
}

// ---------------------------------------------------------------- attention on MFMA
// grid (R/32, HEADS), 256 threads = 4 waves. Wave w handles kt = w, w+4, ...
// LDS map (bytes):
//   [     0, 65536)  Ks  per-wave [64][128] bf16, XOR-swizzled rows
//   [ 65536,131072)  Vt  per-wave [128][64] bf16, XOR-swizzled rows
//   [131072,149504)  Ash per-wave [32][72] bf16 (P round-trip)
//   [149504,153600)  caS per-wave [64][4] f32 (ca.xyz, maskK)
//   after-loop alias: Ored [4][32][132] f32 @0, dred [4][32][4] f32 @67584
__global__ __launch_bounds__(256, 1) void attn_mfma(
    const unsigned short* __restrict__ qf, const unsigned short* __restrict__ kf,
    const unsigned short* __restrict__ vt,
    const float* __restrict__ ca, const float* __restrict__ cb,
    const float* __restrict__ fr, const float* __restrict__ maskf,
    float* __restrict__ fa)
{
    __shared__ __align__(16) char smem[153600];
    const int tid = threadIdx.x;
    const int w = tid >> 6, lane = tid & 63;
    const int cL = lane & 15, gL = lane >> 4;
    const int qbase = blockIdx.x * 32;
    const int h = blockIdx.y;

    char* KsW  = smem + w*16384;
    char* VtW  = smem + 65536 + w*16384;
    char* AshW = smem + 131072 + w*4608;
    char* caSW = smem + 149504 + w*1024;

    // Q fragments held in registers for the whole kernel: A[m=q][k=d]
    bf16x8 qfrag[2][4];
    #pragma unroll
    for (int mt = 0; mt < 2; mt++)
        #pragma unroll
        for (int ks = 0; ks < 4; ks++)
            qfrag[mt][ks] = *(const bf16x8*)(qf + (size_t)(qbase + mt*16 + cL)*H_
                                             + h*HD_ + ks*32 + gL*8);
    float mq[2][4];
    #pragma unroll
    for (int mt = 0; mt < 2; mt++)
        #pragma unroll
        for (int j = 0; j < 4; j++)
            mq[mt][j] = (maskf[qbase + mt*16 + gL*4 + j] > 0.f) ? 1.f : 0.f;

    f32x4 O[2][8] = {};
    float den[2][4] = {}, axv[2][4] = {}, ayv[2][4] = {}, azv[2][4] = {};

    const unsigned short* kbase = kf + h*HD_;
    const unsigned short* vbase = vt + (size_t)h*HD_*R_;

    for (int kt = w; kt < R_/64; kt += 4) {
        const int kb = kt * 64;
        // ---- stage (batched loads first, then LDS stores)
        u32x4 tK[16], tV[16];
        #pragma unroll
        for (int j = 0; j < 16; j++) {
            int flat = j*64 + lane;
            tK[j] = *(const u32x4*)(kbase + (size_t)(kb + (flat>>4))*H_ + (flat&15)*8);
        }
        #pragma unroll
        for (int j = 0; j < 16; j++) {
            int flat = j*64 + lane;
            tV[j] = *(const u32x4*)(vbase + (size_t)(flat>>3)*R_ + kb + (flat&7)*8);
        }
        f32x4 cav4;
        cav4[0] = ca[(kb+lane)*3+0]; cav4[1] = ca[(kb+lane)*3+1];
        cav4[2] = ca[(kb+lane)*3+2]; cav4[3] = maskf[kb+lane];
        #pragma unroll
        for (int j = 0; j < 16; j++) {
            int flat = j*64 + lane;
            int row = flat>>4, c = flat&15;
            *(u32x4*)(KsW + row*256 + ((c*16) ^ ((row&7)<<4))) = tK[j];
        }
        #pragma unroll
        for (int j = 0; j < 16; j++) {
            int flat = j*64 + lane;
            int d = flat>>3, c = flat&7;
            *(u32x4*)(VtW + d*128 + ((c*16) ^ ((d&7)<<4))) = tV[j];
        }
        *(f32x4*)(caSW + lane*16) = cav4;

        // ---- QK^T: S[2mt][4nt] tiles, K-dim 128 = 4 mfma steps
        f32x4 sacc[2][4] = {};
        #pragma unroll
        for (int nt = 0; nt < 4; nt++) {
            int n = nt*16 + cL;                      // key row in tile
            int rs = (n&7)<<4;
            bf16x8 k0 = *(const bf16x8*)(KsW + n*256 + (((0*4+gL)*16) ^ rs));
            bf16x8 k1 = *(const bf16x8*)(KsW + n*256 + (((1*4+gL)*16) ^ rs));
            bf16x8 k2 = *(const bf16x8*)(KsW + n*256 + (((2*4+gL)*16) ^ rs));
            bf16x8 k3 = *(const bf16x8*)(KsW + n*256 + (((3*4+gL)*16) ^ rs));
            #pragma unroll
            for (int mt = 0; mt < 2; mt++) {
                sacc[mt][nt] = __builtin_amdgcn_mfma_f32_16x16x32_bf16(qfrag[mt][0], k0, sacc[mt][nt], 0,0,0);
                sacc[mt][nt] = __builtin_amdgcn_mfma_f32_16x16x32_bf16(qfrag[mt][1], k1, sacc[mt][nt], 0,0,0);
                sacc[mt][nt] = __builtin_amdgcn_mfma_f32_16x16x32_bf16(qfrag[mt][2], k2, sacc[mt][nt], 0,0,0);
                sacc[mt][nt] = __builtin_amdgcn_mfma_f32_16x16x32_bf16(qfrag[mt][3], k3, sacc[mt][nt], 0,0,0);
            }
        }

        // ---- exp + den/pos accumulate + P->bf16 into Ash
        // C layout: col(key-in-tile)=lane&15, row(q-in-tile)=(lane>>4)*4+j
        unsigned short* arow = (unsigned short*)AshW;
        #pragma unroll
        for (int nt = 0; nt < 4; nt++) {
            f32x4 cav = *(const f32x4*)(caSW + (nt*16 + cL)*16);
            #pragma unroll
            for (int mt = 0; mt < 2; mt++) {
                f32x4 s4 = sacc[mt][nt];
                float av[4];
                #pragma unroll
                for (int j = 0; j < 4; j++) {
                    float a = __expf(fminf(s4[j], 75.f)) * cav[3] * mq[mt][j];
                    if (!(a < 3.0e38f)) a = 0.f;
                    av[j] = a;
                    den[mt][j] += a;
                    axv[mt][j] += a * cav[0];
                    ayv[mt][j] += a * cav[1];
                    azv[mt][j] += a * cav[2];
                }
                unsigned int p01, p23;
                asm("v_cvt_pk_bf16_f32 %0, %1, %2" : "=v"(p01) : "v"(av[0]), "v"(av[1]));
                asm("v_cvt_pk_bf16_f32 %0, %1, %2" : "=v"(p23) : "v"(av[2]), "v"(av[3]));
                int qr = mt*16 + gL*4;
                int col = nt*16 + cL;
                arow[(qr+0)*72 + col] = (unsigned short)p01;
                arow[(qr+1)*72 + col] = (unsigned short)(p01 >> 16);
                arow[(qr+2)*72 + col] = (unsigned short)p23;
                arow[(qr+3)*72 + col] = (unsigned short)(p23 >> 16);
            }
        }

        // ---- PV: O[m=q][n=d] += P[q][key] * V[key][d], K-dim 64 = 2 steps
        #pragma unroll
        for (int ks = 0; ks < 2; ks++) {
            bf16x8 pa0 = *(const bf16x8*)(AshW + ((size_t)(cL)*72      + ks*32 + gL*8)*2);
            bf16x8 pa1 = *(const bf16x8*)(AshW + ((size_t)(16 + cL)*72 + ks*32 + gL*8)*2);
            #pragma unroll
            for (int dt = 0; dt < 8; dt++) {
                int d = dt*16 + cL;
                bf16x8 vb = *(const bf16x8*)(VtW + d*128 + (((ks*4+gL)*16) ^ ((d&7)<<4)));
                O[0][dt] = __builtin_amdgcn_mfma_f32_16x16x32_bf16(pa0, vb, O[0][dt], 0,0,0);
                O[1][dt] = __builtin_amdgcn_mfma_f32_16x16x32_bf16(pa1, vb, O[1][dt], 0,0,0);
            }
        }
    }

    // ---- cross-wave reduction (LDS reused; all waves done with Ks/Vt)
    __syncthreads();
    float* Ored = (float*)smem;            // [4][32][132]
    float* dred = (float*)(smem + 67584);  // [4][32][4]  (den, ax, ay, az)
    #pragma unroll
    for (int mt = 0; mt < 2; mt++)
        #pragma unroll
        for (int dt = 0; dt < 8; dt++) {
            f32x4 o4 = O[mt][dt];
            #pragma unroll
            for (int j = 0; j < 4; j++)
                Ored[w*4224 + (mt*16 + gL*4 + j)*132 + dt*16 + cL] = o4[j];
        }
    #pragma unroll
    for (int mt = 0; mt < 2; mt++)
        #pragma unroll
        for (int j = 0; j < 4; j++) {
            float d0 = den[mt][j], x0 = axv[mt][j], y0 = ayv[mt][j], z0 = azv[mt][j];
            #pragma unroll
            for (int off = 8; off >= 1; off >>= 1) {
                d0 += __shfl_xor(d0, off); x0 += __shfl_xor(x0, off);
                y0 += __shfl_xor(y0, off); z0 += __shfl_xor(z0, off);
            }
            if (cL == 0) {
                f32x4 v; v[0]=d0; v[1]=x0; v[2]=y0; v[3]=z0;
                *(f32x4*)&dred[w*128 + (mt*16 + gL*4 + j)*4] = v;
            }
        }
    __syncthreads();
    // feat_node: each thread finalizes 16 d-values of one q-row
    {
        int q = tid >> 3, d0 = (tid & 7) * 16;
        float dn = dred[q*4] + dred[128 + q*4] + dred[256 + q*4] + dred[384 + q*4];
        float inv = (dn > 0.f) ? 1.f/dn : 0.f;
        size_t rowb = (size_t)(qbase+q)*FA_LD + h*HD_ + d0;
        #pragma unroll
        for (int e = 0; e < 4; e++) {
            f32x4 s = *(const f32x4*)&Ored[q*132 + d0 + e*4];
            #pragma unroll
            for (int ww = 1; ww < 4; ww++)
                s += *(const f32x4*)&Ored[ww*4224 + q*132 + d0 + e*4];
            *(f32x4*)&fa[rowb + e*4] = s * inv;
        }
    }
    // spatial features (one thread per q-row)
    if (tid < 32) {
        float dn = dred[tid*4+0] + dred[128+tid*4+0] + dred[256+tid*4+0] + dred[384+tid*4+0];
        float ax = dred[tid*4+1] + dred[128+tid*4+1] + dred[256+tid*4+1] + dred[384+tid*4+1];
        float ay = dred[tid*4+2] + dred[128+tid*4+2] + dred[256+tid*4+2] + dred[384+tid*4+2];
        float az = dred[tid*4+3] + dred[128+tid*4+3] + dred[256+tid*4+3] + dred[384+tid*4+3];
        float inv = (dn > 0.f) ? 1.f/dn : 0.f;
        float live = (dn > 0.f) ? 1.f : 0.f;
        int qg = qbase + tid;
        float b0 = cb[qg*3+0]*live - ax*inv;
        float b1 = cb[qg*3+1]*live - ay*inv;
        float b2 = cb[qg*3+2]*live - az*inv;
        float dist = sqrtf(b0*b0 + b1*b1 + b2*b2);
        const float* F = fr + (size_t)qg*9;
        float p0 = F[0]*b0 + F[1]*b1 + F[2]*b2;
        float p1 = F[3]*b0 + F[4]*b1 + F[5]*b2;
        float p2 = F[6]*b0 + F[7]*b1 + F[8]*b2;
        float pn = sqrtf(p0*p0 + p1*p1 + p2*p2) + 1e-10f;
        size_t rb = (size_t)qg * FA_LD;
        fa[rb + 512 + h*3 + 0] = p0;
        fa[rb + 512 + h*3 + 1] = p1;
        fa[rb + 512 + h*3 + 2] = p2;
        fa[rb + 524 + h]       = dist;
        fa[rb + 528 + h*3 + 0] = p0/pn;
        fa[rb + 528 + h*3 + 1] = p1/pn;
        fa[rb + 528 + h*3 + 2] = p2/pn;
        if (h == 0) { fa[rb+540]=0.f; fa[rb+541]=0.f; fa[rb+542]=0.f; fa[rb+543]=0.f; }
    }
}

// ---------------------------------------------------------------- Wo tiled GEMM (R17 verbatim)
__global__ __launch_bounds__(256) void wo_tile(
    const float* __restrict__ fa, const void* __restrict__ Wo,
    const void* __restrict__ bo, float* __restrict__ Y,
    const int* __restrict__ flag)
{
    __shared__ __align__(16) float Xs[32][68];   // [k][m]
    __shared__ __align__(16) float Wsh[32][68];  // [k][n]
    const int tid = threadIdx.x;
    const int mbase = blockIdx.x * 64;
    const int nbase = blockIdx.y * 64;
    bool f32 = *flag != 0;
    const int tm = tid >> 4, tn = tid & 15;
    float acc[4][4] = {};
    for (int kt = 0; kt < 17; kt++) {
        const int k0 = kt * 32;
        __syncthreads();
        for (int i = tid; i < 64*32; i += 256) {
            int m = i >> 5, kk = i & 31;
            Xs[kk][m] = fa[(size_t)(mbase+m)*FA_LD + k0 + kk];
        }
        for (int i = tid; i < 32*64; i += 256) {
            int kk = i >> 6, nn = i & 63;
            int krow = k0 + kk;
            Wsh[kk][nn] = (krow < 540) ? loadf(Wo, (size_t)krow*H_ + nbase + nn, f32) : 0.f;
        }
        __syncthreads();
        for (int k = 0; k < 32; k++) {
            f32x4 a = *(const f32x4*)&Xs[k][tm*4];
            f32x4 b = *(const f32x4*)&Wsh[k][tn*4];
            #pragma unroll
            for (int i = 0; i < 4; i++)
                #pragma unroll
                for (int j = 0; j < 4; j++)
                    acc[i][j] += a[i] * b[j];
        }
    }
    #pragma unroll
    for (int i = 0; i < 4; i++) {
        int m = mbase + tm*4 + i;
        #pragma unroll
        for (int j = 0; j < 4; j++) {
            int n = nbase + tn*4 + j;
            Y[(size_t)m*H_ + n] = acc[i][j] + loadf(bo, n, f32);
        }
    }
}

// ---------------------------------------------------------------- relu+LN1+mask+res+LN2 (R17 verbatim)
__global__ __launch_bounds__(256) void final_ln(
    const float* __restrict__ Y, const void* __restrict__ nf,
    const int* __restrict__ cai, const float* __restrict__ maskf,
    const void* __restrict__ g1, const void* __restrict__ b1,
    const void* __restrict__ g2, const void* __restrict__ b2,
    void* __restrict__ out, const int* __restrict__ flag)
{
    const int tid = threadIdx.x, lane = tid & 63, wave = tid >> 6;
    const int r = blockIdx.x * 4 + wave;
    bool f32 = *flag != 0;
    const float mk = maskf[r];
    const size_t xrow = (size_t)cai[r] * H_;
    float y[8], s1 = 0.f, s2 = 0.f;
    #pragma unroll
    for (int i = 0; i < 8; i++) {
        int c = lane + i*64;
        float v = fmaxf(Y[(size_t)r*H_ + c], 0.f);
        y[i] = v; s1 += v; s2 += v*v;
    }
    #pragma unroll
    for (int off = 32; off; off >>= 1) { s1 += __shfl_xor(s1, off); s2 += __shfl_xor(s2, off); }
    float mu = s1 * (1.f/H_);
    float var = s2 * (1.f/H_) - mu*mu;
    float rstd = rsqrtf(fmaxf(var, 0.f) + 1e-5f);
    float t[8], u1 = 0.f, u2 = 0.f;
    #pragma unroll
    for (int i = 0; i < 8; i++) {
        int c = lane + i*64;
        float hh = (y[i]-mu)*rstd*loadf(g1, c, f32) + loadf(b1, c, f32);
        hh *= mk;
        float tv = loadf(nf, xrow + c, f32) + hh;
        t[i] = tv; u1 += tv; u2 += tv*tv;
    }
    #pragma unroll
    for (int off = 32; off; off >>= 1) { u1 += __shfl_xor(u1, off); u2 += __shfl_xor(u2, off); }
    float mu2 = u1 * (1.f/H_);
    float var2 = u2 * (1.f/H_) - mu2*mu2;
    float rstd2 = rsqrtf(fmaxf(var2, 0.f) + 1e-5f);
    #pragma unroll
    for (int i = 0; i < 8; i++) {
        int c = lane + i*64;
        float ov = (t[i]-mu2)*rstd2*loadf(g2, c, f32) + loadf(b2, c, f32);
        if (f32) ((float*)out)[(size_t)r*H_ + c] = ov;
        else ((unsigned short*)out)[(size_t)r*H_ + c] = f2bf(ov);
    }
}

// ---------------------------------------------------------------- launch
extern "C" void kernel_launch(void* const* d_in, const int* in_sizes, int n_in,
                              void* d_out, int out_size, void* d_ws, size_t ws_size,
                              hipStream_t stream)
{
    static const int expected[16] = {
        8388608, 49152, 262144, 512, 262144, 512, 262144, 512,
        276480, 512, 512, 512, 512, 512, 16384, 16384
    };
    if (n_in != 16) {
        diag<<<dim3(1), dim3(64), 0, stream>>>((unsigned short*)d_out, 1000.f + n_in);
        return;
    }
    for (int i = 0; i < 16; i++) {
        if (in_sizes[i] != expected[i]) {
            diag<<<dim3(1), dim3(64), 0, stream>>>((unsigned short*)d_out, 2000.f + 10.f*i);
            return;
        }
    }
    const size_t smallEnd = 1u << 20;
    const size_t qkvBytes = (size_t)R_*H_*2;     // bf16 always
    const size_t faBytes = (size_t)R_*FA_LD*4;
    const size_t needBF16 = smallEnd + 3*qkvBytes + faBytes;
    if (ws_size < needBF16) {
        diag<<<dim3(1), dim3(64), 0, stream>>>((unsigned short*)d_out, 3000.f);
        return;
    }

    const void* nf  = d_in[0];
    const void* pos = d_in[1];
    const void* Wq  = d_in[2];  const void* bq = d_in[3];
    const void* Wk  = d_in[4];  const void* bk = d_in[5];
    const void* Wv  = d_in[6];  const void* bv = d_in[7];
    const void* Wo  = d_in[8];  const void* bo = d_in[9];
    const void* g1  = d_in[10]; const void* b1 = d_in[11];
    const void* g2  = d_in[12]; const void* b2 = d_in[13];
    const int* atype = (const int*)d_in[14];

    char* ws = (char*)d_ws;
    int*   flag  = (int*)  (ws + 0);
    int*   cai   = (int*)  (ws + 1024);
    float* ca    = (float*)(ws + 9216);
    float* cb    = (float*)(ws + 33792);
    float* fr    = (float*)(ws + 58368);
    float* maskf = (float*)(ws + 132096);
    void*  qf = ws + smallEnd;
    void*  kf = ws + smallEnd + qkvBytes;
    void*  vt = ws + smallEnd + 2*qkvBytes;      // V transposed [4][128][2048] bf16
    float* fa = (float*)(ws + smallEnd + 3*qkvBytes);
    float* Y  = (float*)qf;   // aliases qf+kf (4 MB f32) — both dead after attn

    detect_dtype<<<dim3(1), dim3(256), 0, stream>>>((const unsigned short*)nf, flag);
    gather_frames<<<dim3(8), dim3(256), 0, stream>>>(pos, atype, flag, cai, ca, cb, fr, maskf);
    qkv_tile<<<dim3(R_/64, 24), dim3(256), 0, stream>>>(nf, cai, Wq, Wk, Wv, bq, bk, bv,
                                                        qf, kf, vt, flag);
    attn_mfma<<<dim3(R_/32, HEADS_), dim3(256), 0, stream>>>(
        (const unsigned short*)qf, (const unsigned short*)kf, (const unsigned short*)vt,
        ca, cb, fr, maskf, fa);
    wo_tile<<<dim3(R_/64, H_/64), dim3(256), 0, stream>>>(fa, Wo, bo, Y, flag);
    final_ln<<<dim3(512), dim3(256), 0, stream>>>(Y, nf, cai, maskf, g1, b1, g2, b2,
                                                  d_out, flag);
}

// Round 3
// 211.812 us; speedup vs baseline: 2.7850x; 1.6709x over previous
//
#include <hip/hip_runtime.h>
#include <hip/hip_bf16.h>
#include <stdint.h>

// GeometricGNN on MI355X. R=2048, APR=8, H=512, HEADS=4, HD=128, SD=28.
// Round 20: qkv_tile / wo_tile scalar GEMMs replaced by MFMA GEMMs with
// split-bf16 (hi+lo) 3-pass accumulation => fp32-grade accuracy.
//  - pack_prep: gathers X rows (cai) and splits to bf16 hi/lo planes;
//    transposes+splits Wqkv -> [1536][512] and Wo -> [512][544] hi/lo planes.
//  - qkv_mfma: 128x128 tile/block, 4 waves (64x64 quadrant each), K-step 32,
//    prefetch regs -> LDS (XOR-swizzled), 48 mfma/step/wave (3 split terms).
//    Q/K stored bf16 row-major via LDS-transpose epilogue; V stored bf16
//    TRANSPOSED directly (MFMA C-layout is column-natural).
//  - wo_mfma: same structure, K=544 (17 steps), fa split in-kernel, Y f32.
//  - attn_mfma / gather / final_ln: R19 verbatim.
// X hi/lo planes alias the fa region (dead until attn writes fa after qkv).

#define R_ 2048
#define APR_ 8
#define H_ 512
#define HEADS_ 4
#define HD_ 128
#define FA_LD 544

typedef __attribute__((ext_vector_type(4))) float f32x4;
typedef __attribute__((ext_vector_type(4))) unsigned int u32x4;
typedef __attribute__((ext_vector_type(4))) unsigned short us4;
typedef __bf16 bf16x8 __attribute__((ext_vector_type(8)));

static __device__ __forceinline__ float bf2f(unsigned short u) {
    union { unsigned int i; float f; } c; c.i = ((unsigned int)u) << 16; return c.f;
}
static __device__ __forceinline__ unsigned short f2bf(float f) {
    union { float f; unsigned int i; } c; c.f = f;
    unsigned int r = c.i + 0x7fffu + ((c.i >> 16) & 1u);   // RNE
    return (unsigned short)(r >> 16);
}
static __device__ __forceinline__ float san(float v) {
    return (v == v && fabsf(v) < 1e30f) ? v : 0.f;
}
// flag-aware, sanitized load of logical element i of a float input array
static __device__ __forceinline__ float loadf(const void* p, size_t i, bool f32) {
    float v = f32 ? ((const float*)p)[i] : bf2f(((const unsigned short*)p)[i]);
    return (v == v && fabsf(v) < 1e30f) ? v : 0.f;
}

// ---------------------------------------------------------------- diag
__global__ void diag(unsigned short* out, float val) {
    if (threadIdx.x == 0 && blockIdx.x == 0) out[0] = f2bf(val);
}

// ---------------------------------------------------------------- dtype detect (d_in[0])
__global__ void detect_dtype(const unsigned short* __restrict__ nf, int* flag) {
    __shared__ int bad;
    if (threadIdx.x == 0) bad = 0;
    __syncthreads();
    int cnt = 0;
    for (int i = threadIdx.x; i < 8192; i += 256) {
        unsigned e = (nf[i] >> 7) & 0xFFu;
        if (e >= 0xC0u) cnt++;
    }
    atomicAdd(&bad, cnt);
    __syncthreads();
    if (threadIdx.x == 0) *flag = (bad > 16) ? 1 : 0;
}

// ---------------------------------------------------------------- gather + frames (R17 verbatim)
__global__ void gather_frames(const void* __restrict__ pos,
                              const int* __restrict__ atype,
                              const int* __restrict__ flag,
                              int* __restrict__ cai, float* __restrict__ ca,
                              float* __restrict__ cb, float* __restrict__ fr,
                              float* __restrict__ maskf)
{
    int r = blockIdx.x * blockDim.x + threadIdx.x;
    if (r >= R_) return;
    bool f32 = *flag != 0;
    int base = r * APR_;
    float caP[3] = {0,0,0}, cbP[3] = {0,0,0};
    int idx = base; bool h0=false, h1=false, h2=false;
    for (int a = 0; a < APR_; a++) {
        int t = atype[base + a];
        if (t == 0) h0 = true;
        if (t == 2) h2 = true;
        if (t == 1) { h1 = true; idx = base + a;
            for (int j = 0; j < 3; j++) caP[j] += loadf(pos, (size_t)(base+a)*3 + j, f32); }
        if (t == 4) {
            for (int j = 0; j < 3; j++) cbP[j] += loadf(pos, (size_t)(base+a)*3 + j, f32); }
    }
    float s = fabsf(cbP[0]) + fabsf(cbP[1]) + fabsf(cbP[2]);
    if (s < 1e-6f) { cbP[0]=caP[0]; cbP[1]=caP[1]; cbP[2]=caP[2]; }
    float e1[3] = { cbP[0]-caP[0], cbP[1]-caP[1], cbP[2]-caP[2] };
    float n1 = sqrtf(e1[0]*e1[0] + e1[1]*e1[1] + e1[2]*e1[2]);
    float e1u[3] = { e1[0], e1[1], e1[2] };
    if (n1 > 1e-6f) { float iv = 1.f / fmaxf(n1, 1e-6f); e1u[0]*=iv; e1u[1]*=iv; e1u[2]*=iv; }
    float e2a[3] = { e1u[1], -e1u[0], 0.f };
    float n2a = sqrtf(e2a[0]*e2a[0] + e2a[1]*e2a[1]);
    float e2b[3] = { -e1u[2], 0.f, e1u[0] };
    float n2b = sqrtf(e2b[0]*e2b[0] + e2b[2]*e2b[2]);
    bool useb = n2a < 1e-6f;
    float e2[3] = { useb?e2b[0]:e2a[0], useb?e2b[1]:e2a[1], useb?e2b[2]:e2a[2] };
    float n2 = useb ? n2b : n2a;
    float iv2 = 1.f / fmaxf(n2, 1e-6f);
    float e2u[3] = { e2[0]*iv2, e2[1]*iv2, e2[2]*iv2 };
    float e3[3] = { e1u[1]*e2u[2]-e1u[2]*e2u[1],
                    e1u[2]*e2u[0]-e1u[0]*e2u[2],
                    e1u[0]*e2u[1]-e1u[1]*e2u[0] };
    bool ok = (r < R_-1) && (n1 > 1e-6f) && (n2 > 1e-6f);
    float F[9];
    if (ok) { F[0]=e1u[0]; F[1]=e2u[0]; F[2]=e3[0];
              F[3]=e1u[1]; F[4]=e2u[1]; F[5]=e3[1];
              F[6]=e1u[2]; F[7]=e2u[2]; F[8]=e3[2]; }
    else    { F[0]=1;F[1]=0;F[2]=0; F[3]=0;F[4]=1;F[5]=0; F[6]=0;F[7]=0;F[8]=1; }
    cai[r] = idx;
    for (int j = 0; j < 3; j++) { ca[r*3+j] = caP[j]; cb[r*3+j] = cbP[j]; }
    for (int j = 0; j < 9; j++) fr[r*9+j] = F[j];
    maskf[r] = (h0 && h1 && h2) ? 1.f : 0.f;
}

// ---------------------------------------------------------------- pack_prep
// bid <1024: gather X rows, split -> xg_hi/xg_lo [2048][512] bf16
// 1024..1791: transpose+split Wqkv -> wqt_hi/lo [1536][512] bf16
// 1792..2063: transpose+split+pad Wo -> wot_hi/lo [512][544] bf16
__global__ __launch_bounds__(256) void pack_prep(
    const void* __restrict__ nf, const int* __restrict__ cai,
    const void* __restrict__ Wq, const void* __restrict__ Wk, const void* __restrict__ Wv,
    const void* __restrict__ Wo,
    unsigned short* __restrict__ xg_hi, unsigned short* __restrict__ xg_lo,
    unsigned short* __restrict__ wqt_hi, unsigned short* __restrict__ wqt_lo,
    unsigned short* __restrict__ wot_hi, unsigned short* __restrict__ wot_lo,
    const int* __restrict__ flag)
{
    const bool f32 = *flag != 0;
    const int bid = blockIdx.x, tid = threadIdx.x;
    us4 h4, l4;
    if (bid < 1024) {
        int flat = bid*256 + tid;            // row*128 + kc
        int row = flat >> 7, kc = flat & 127;
        size_t src = (size_t)cai[row]*H_ + kc*4;
        #pragma unroll
        for (int i = 0; i < 4; i++) {
            float v = loadf(nf, src + i, f32);
            unsigned short hb = f2bf(v);
            h4[i] = hb; l4[i] = f2bf(v - bf2f(hb));
        }
        *(us4*)(xg_hi + (size_t)row*H_ + kc*4) = h4;
        *(us4*)(xg_lo + (size_t)row*H_ + kc*4) = l4;
    } else if (bid < 1792) {
        int flat = (bid-1024)*256 + tid;     // kc*1536 + nn
        int kc = flat / 1536, nn = flat - kc*1536;
        int mat = nn >> 9, ncol = nn & 511;
        const void* W = (mat==0) ? Wq : (mat==1) ? Wk : Wv;
        #pragma unroll
        for (int i = 0; i < 4; i++) {
            float v = loadf(W, (size_t)(kc*4+i)*H_ + ncol, f32);
            unsigned short hb = f2bf(v);
            h4[i] = hb; l4[i] = f2bf(v - bf2f(hb));
        }
        *(us4*)(wqt_hi + (size_t)nn*H_ + kc*4) = h4;
        *(us4*)(wqt_lo + (size_t)nn*H_ + kc*4) = l4;
    } else {
        int flat = (bid-1792)*256 + tid;     // kc*512 + n, kc 0..135
        int kc = flat >> 9, n = flat & 511;
        #pragma unroll
        for (int i = 0; i < 4; i++) {
            int k = kc*4 + i;
            float v = (k < 540) ? loadf(Wo, (size_t)k*H_ + n, f32) : 0.f;
            unsigned short hb = f2bf(v);
            h4[i] = hb; l4[i] = f2bf(v - bf2f(hb));
        }
        *(us4*)(wot_hi + (size_t)n*FA_LD + kc*4) = h4;
        *(us4*)(wot_lo + (size_t)n*FA_LD + kc*4) = l4;
    }
}

// ---------------------------------------------------------------- QKV MFMA GEMM
// C[2048x1536] = X[2048x512] * W[512x1536], split-bf16 3-term accumulation.
// grid (16, 12), 256 thr = 4 waves, block tile 128x128, wave quadrant 64x64.
__global__ __launch_bounds__(256, 1) void qkv_mfma(
    const unsigned short* __restrict__ xg_hi, const unsigned short* __restrict__ xg_lo,
    const unsigned short* __restrict__ wqt_hi, const unsigned short* __restrict__ wqt_lo,
    const void* __restrict__ bq, const void* __restrict__ bk, const void* __restrict__ bv,
    unsigned short* __restrict__ qf, unsigned short* __restrict__ kf,
    unsigned short* __restrict__ vt, const int* __restrict__ flag)
{
    __shared__ __align__(16) char smem[33792];
    char* Xhi = smem;
    char* Xlo = smem + 8192;
    char* Bhi = smem + 16384;
    char* Blo = smem + 24576;
    const int tid = threadIdx.x;
    const int w = tid >> 6, lane = tid & 63, cL = lane & 15, gL = lane >> 4;
    const int wm = w >> 1, wn = w & 1;
    const int mbase = blockIdx.x * 128;
    const int nblk  = blockIdx.y * 128;
    const int mat = nblk >> 9, ncol0 = nblk & 511;
    const bool f32 = *flag != 0;
    const unsigned short* ahg = xg_hi + (size_t)mbase * H_;
    const unsigned short* alg = xg_lo + (size_t)mbase * H_;
    const unsigned short* bhg = wqt_hi + (size_t)nblk * H_;
    const unsigned short* blg = wqt_lo + (size_t)nblk * H_;

    u32x4 va[4], vb[4];
#define QKV_LOAD(K0)                                                          \
    {                                                                         \
        _Pragma("unroll")                                                     \
        for (int i = 0; i < 4; i++) {                                         \
            int flat = i*256 + tid, pl = flat >> 9, rem = flat & 511;         \
            int row = rem >> 2, c16 = rem & 3;                                \
            const unsigned short* pa = pl ? alg : ahg;                        \
            va[i] = *(const u32x4*)(pa + (size_t)row*H_ + (K0) + c16*8);      \
        }                                                                     \
        _Pragma("unroll")                                                     \
        for (int i = 0; i < 4; i++) {                                         \
            int flat = i*256 + tid, pl = flat >> 9, rem = flat & 511;         \
            int row = rem >> 2, c16 = rem & 3;                                \
            const unsigned short* pb = pl ? blg : bhg;                        \
            vb[i] = *(const u32x4*)(pb + (size_t)row*H_ + (K0) + c16*8);      \
        }                                                                     \
    }
    QKV_LOAD(0)
    f32x4 acc[4][4] = {};
    for (int kt = 0; kt < 16; kt++) {
        __syncthreads();
        #pragma unroll
        for (int i = 0; i < 4; i++) {
            int flat = i*256 + tid, pl = flat >> 9, rem = flat & 511;
            int row = rem >> 2, c16 = rem & 3;
            char* p = pl ? Xlo : Xhi;
            *(u32x4*)(p + row*64 + ((c16*16) ^ (((row>>1)&3)<<4))) = va[i];
        }
        #pragma unroll
        for (int i = 0; i < 4; i++) {
            int flat = i*256 + tid, pl = flat >> 9, rem = flat & 511;
            int row = rem >> 2, c16 = rem & 3;
            char* p = pl ? Blo : Bhi;
            *(u32x4*)(p + row*64 + ((c16*16) ^ (((row>>1)&3)<<4))) = vb[i];
        }
        __syncthreads();
        if (kt < 15) QKV_LOAD((kt+1)*32)
        bf16x8 ah[4], al[4], bh[4], bl[4];
        #pragma unroll
        for (int ms = 0; ms < 4; ms++) {
            int row = wm*64 + ms*16 + cL;
            int off = row*64 + ((gL*16) ^ (((row>>1)&3)<<4));
            ah[ms] = *(const bf16x8*)(Xhi + off);
            al[ms] = *(const bf16x8*)(Xlo + off);
        }
        #pragma unroll
        for (int ns = 0; ns < 4; ns++) {
            int row = wn*64 + ns*16 + cL;
            int off = row*64 + ((gL*16) ^ (((row>>1)&3)<<4));
            bh[ns] = *(const bf16x8*)(Bhi + off);
            bl[ns] = *(const bf16x8*)(Blo + off);
        }
        #pragma unroll
        for (int ms = 0; ms < 4; ms++)
            #pragma unroll
            for (int ns = 0; ns < 4; ns++) {
                acc[ms][ns] = __builtin_amdgcn_mfma_f32_16x16x32_bf16(ah[ms], bh[ns], acc[ms][ns], 0,0,0);
                acc[ms][ns] = __builtin_amdgcn_mfma_f32_16x16x32_bf16(ah[ms], bl[ns], acc[ms][ns], 0,0,0);
                acc[ms][ns] = __builtin_amdgcn_mfma_f32_16x16x32_bf16(al[ms], bh[ns], acc[ms][ns], 0,0,0);
            }
    }
#undef QKV_LOAD
    const void* bias = (mat==0) ? bq : (mat==1) ? bk : bv;
    if (mat == 2) {
        // V: direct transposed store  vt[col][2048]
        #pragma unroll
        for (int ns = 0; ns < 4; ns++) {
            int ncol = ncol0 + wn*64 + ns*16 + cL;
            float bc = loadf(bias, ncol, f32);
            #pragma unroll
            for (int ms = 0; ms < 4; ms++) {
                int m0 = mbase + wm*64 + ms*16 + gL*4;
                us4 pk;
                #pragma unroll
                for (int j = 0; j < 4; j++) pk[j] = f2bf(acc[ms][ns][j] + bc);
                *(us4*)(vt + (size_t)ncol*R_ + m0) = pk;
            }
        }
    } else {
        // Q/K: LDS transpose epilogue (2 halves of the 64x64 quadrant)
        unsigned short* dst = (mat==0) ? qf : kf;
        float* ep = (float*)smem + w*2112;     // [32][66] per wave
        #pragma unroll
        for (int half = 0; half < 2; half++) {
            __syncthreads();
            #pragma unroll
            for (int ms2 = 0; ms2 < 2; ms2++) {
                int ms = half*2 + ms2;
                #pragma unroll
                for (int ns = 0; ns < 4; ns++)
                    #pragma unroll
                    for (int j = 0; j < 4; j++)
                        ep[(ms2*16 + gL*4 + j)*66 + ns*16 + cL] = acc[ms][ns][j];
            }
            __syncthreads();
            int r = lane >> 1, cp = (lane & 1) * 32;
            int mrow = mbase + wm*64 + half*32 + r;
            #pragma unroll
            for (int c4 = 0; c4 < 8; c4++) {
                int nloc = cp + c4*4;
                int ncol = ncol0 + wn*64 + nloc;
                us4 pk;
                #pragma unroll
                for (int e = 0; e < 4; e++)
                    pk[e] = f2bf(ep[r*66 + nloc + e] + loadf(bias, ncol + e, f32));
                *(us4*)(dst + (size_t)mrow*H_ + ncol) = pk;
            }
        }
    }
}

// ---------------------------------------------------------------- Wo MFMA GEMM
// Y[2048x512] = fa[2048x544] * Wo[544x512], split-bf16 3-term; fa split in-kernel.
// grid (16, 4), block tile 128x128, K-steps 17.
__global__ __launch_bounds__(256, 1) void wo_mfma(
    const float* __restrict__ fa,
    const unsigned short* __restrict__ wot_hi, const unsigned short* __restrict__ wot_lo,
    const void* __restrict__ bo, float* __restrict__ Y,
    const int* __restrict__ flag)
{
    __shared__ __align__(16) char smem[33792];
    char* Ahi = smem;
    char* Alo = smem + 8192;
    char* Bhi = smem + 16384;
    char* Blo = smem + 24576;
    const int tid = threadIdx.x;
    const int w = tid >> 6, lane = tid & 63, cL = lane & 15, gL = lane >> 4;
    const int wm = w >> 1, wn = w & 1;
    const int mbase = blockIdx.x * 128;
    const int nbase = blockIdx.y * 128;
    const bool f32 = *flag != 0;
    const unsigned short* bhg = wot_hi + (size_t)nbase * FA_LD;
    const unsigned short* blg = wot_lo + (size_t)nbase * FA_LD;

    float xv[16];
    u32x4 vb[4];
#define WO_LOAD(K0)                                                           \
    {                                                                         \
        _Pragma("unroll")                                                     \
        for (int i = 0; i < 4; i++) {                                         \
            int flat = i*256 + tid, row = flat >> 3, c4 = flat & 7;           \
            f32x4 t = *(const f32x4*)(fa + (size_t)(mbase+row)*FA_LD + (K0) + c4*4); \
            _Pragma("unroll")                                                 \
            for (int e = 0; e < 4; e++) xv[i*4+e] = t[e];                     \
        }                                                                     \
        _Pragma("unroll")                                                     \
        for (int i = 0; i < 4; i++) {                                         \
            int flat = i*256 + tid, pl = flat >> 9, rem = flat & 511;         \
            int row = rem >> 2, c16 = rem & 3;                                \
            const unsigned short* pb = pl ? blg : bhg;                        \
            vb[i] = *(const u32x4*)(pb + (size_t)row*FA_LD + (K0) + c16*8);   \
        }                                                                     \
    }
    WO_LOAD(0)
    f32x4 acc[4][4] = {};
    for (int kt = 0; kt < 17; kt++) {
        __syncthreads();
        #pragma unroll
        for (int i = 0; i < 4; i++) {
            int flat = i*256 + tid, row = flat >> 3, c4 = flat & 7;
            int sw = ((row>>1)&3) << 4;
            us4 h4, l4;
            #pragma unroll
            for (int e = 0; e < 4; e++) {
                float v = xv[i*4+e];
                unsigned short hb = f2bf(v);
                h4[e] = hb; l4[e] = f2bf(v - bf2f(hb));
            }
            *(us4*)(Ahi + row*64 + ((c4*8) ^ sw)) = h4;
            *(us4*)(Alo + row*64 + ((c4*8) ^ sw)) = l4;
        }
        #pragma unroll
        for (int i = 0; i < 4; i++) {
            int flat = i*256 + tid, pl = flat >> 9, rem = flat & 511;
            int row = rem >> 2, c16 = rem & 3;
            char* p = pl ? Blo : Bhi;
            *(u32x4*)(p + row*64 + ((c16*16) ^ (((row>>1)&3)<<4))) = vb[i];
        }
        __syncthreads();
        if (kt < 16) WO_LOAD((kt+1)*32)
        bf16x8 ah[4], al[4], bh[4], bl[4];
        #pragma unroll
        for (int ms = 0; ms < 4; ms++) {
            int row = wm*64 + ms*16 + cL;
            int off = row*64 + ((gL*16) ^ (((row>>1)&3)<<4));
            ah[ms] = *(const bf16x8*)(Ahi + off);
            al[ms] = *(const bf16x8*)(Alo + off);
        }
        #pragma unroll
        for (int ns = 0; ns < 4; ns++) {
            int row = wn*64 + ns*16 + cL;
            int off = row*64 + ((gL*16) ^ (((row>>1)&3)<<4));
            bh[ns] = *(const bf16x8*)(Bhi + off);
            bl[ns] = *(const bf16x8*)(Blo + off);
        }
        #pragma unroll
        for (int ms = 0; ms < 4; ms++)
            #pragma unroll
            for (int ns = 0; ns < 4; ns++) {
                acc[ms][ns] = __builtin_amdgcn_mfma_f32_16x16x32_bf16(ah[ms], bh[ns], acc[ms][ns], 0,0,0);
                acc[ms][ns] = __builtin_amdgcn_mfma_f32_16x16x32_bf16(ah[ms], bl[ns], acc[ms][ns], 0,0,0);
                acc[ms][ns] = __builtin_amdgcn_mfma_f32_16x16x32_bf16(al[ms], bh[ns], acc[ms][ns], 0,0,0);
            }
    }
#undef WO_LOAD
    // epilogue: LDS transpose, f32 store + bias
    float* ep = (float*)smem + w*2112;
    #pragma unroll
    for (int half = 0; half < 2; half++) {
        __syncthreads();
        #pragma unroll
        for (int ms2 = 0; ms2 < 2; ms2++) {
            int ms = half*2 + ms2;
            #pragma unroll
            for (int ns = 0; ns < 4; ns++)
                #pragma unroll
                for (int j = 0; j < 4; j++)
                    ep[(ms2*16 + gL*4 + j)*66 + ns*16 + cL] = acc[ms][ns][j];
        }
        __syncthreads();
        int r = lane >> 1, cp = (lane & 1) * 32;
        int mrow = mbase + wm*64 + half*32 + r;
        #pragma unroll
        for (int c4 = 0; c4 < 8; c4++) {
            int nloc = cp + c4*4;
            int ncol = nbase + wn*64 + nloc;
            f32x4 o;
            #pragma unroll
            for (int e = 0; e < 4; e++)
                o[e] = ep[r*66 + nloc + e] + loadf(bo, ncol + e, f32);
            *(f32x4*)(Y + (size_t)mrow*H_ + ncol) = o;
        }
    }
}

// ---------------------------------------------------------------- attention on MFMA (R19 verbatim)
__global__ __launch_bounds__(256, 1) void attn_mfma(
    const unsigned short* __restrict__ qf, const unsigned short* __restrict__ kf,
    const unsigned short* __restrict__ vt,
    const float* __restrict__ ca, const float* __restrict__ cb,
    const float* __restrict__ fr, const float* __restrict__ maskf,
    float* __restrict__ fa)
{
    __shared__ __align__(16) char smem[153600];
    const int tid = threadIdx.x;
    const int w = tid >> 6, lane = tid & 63;
    const int cL = lane & 15, gL = lane >> 4;
    const int qbase = blockIdx.x * 32;
    const int h = blockIdx.y;

    char* KsW  = smem + w*16384;
    char* VtW  = smem + 65536 + w*16384;
    char* AshW = smem + 131072 + w*4608;
    char* caSW = smem + 149504 + w*1024;

    bf16x8 qfrag[2][4];
    #pragma unroll
    for (int mt = 0; mt < 2; mt++)
        #pragma unroll
        for (int ks = 0; ks < 4; ks++)
            qfrag[mt][ks] = *(const bf16x8*)(qf + (size_t)(qbase + mt*16 + cL)*H_
                                             + h*HD_ + ks*32 + gL*8);
    float mq[2][4];
    #pragma unroll
    for (int mt = 0; mt < 2; mt++)
        #pragma unroll
        for (int j = 0; j < 4; j++)
            mq[mt][j] = (maskf[qbase + mt*16 + gL*4 + j] > 0.f) ? 1.f : 0.f;

    f32x4 O[2][8] = {};
    float den[2][4] = {}, axv[2][4] = {}, ayv[2][4] = {}, azv[2][4] = {};

    const unsigned short* kbase = kf + h*HD_;
    const unsigned short* vbase = vt + (size_t)h*HD_*R_;

    for (int kt = w; kt < R_/64; kt += 4) {
        const int kb = kt * 64;
        u32x4 tK[16], tV[16];
        #pragma unroll
        for (int j = 0; j < 16; j++) {
            int flat = j*64 + lane;
            tK[j] = *(const u32x4*)(kbase + (size_t)(kb + (flat>>4))*H_ + (flat&15)*8);
        }
        #pragma unroll
        for (int j = 0; j < 16; j++) {
            int flat = j*64 + lane;
            tV[j] = *(const u32x4*)(vbase + (size_t)(flat>>3)*R_ + kb + (flat&7)*8);
        }
        f32x4 cav4;
        cav4[0] = ca[(kb+lane)*3+0]; cav4[1] = ca[(kb+lane)*3+1];
        cav4[2] = ca[(kb+lane)*3+2]; cav4[3] = maskf[kb+lane];
        #pragma unroll
        for (int j = 0; j < 16; j++) {
            int flat = j*64 + lane;
            int row = flat>>4, c = flat&15;
            *(u32x4*)(KsW + row*256 + ((c*16) ^ ((row&7)<<4))) = tK[j];
        }
        #pragma unroll
        for (int j = 0; j < 16; j++) {
            int flat = j*64 + lane;
            int d = flat>>3, c = flat&7;
            *(u32x4*)(VtW + d*128 + ((c*16) ^ ((d&7)<<4))) = tV[j];
        }
        *(f32x4*)(caSW + lane*16) = cav4;

        f32x4 sacc[2][4] = {};
        #pragma unroll
        for (int nt = 0; nt < 4; nt++) {
            int n = nt*16 + cL;
            int rs = (n&7)<<4;
            bf16x8 k0 = *(const bf16x8*)(KsW + n*256 + (((0*4+gL)*16) ^ rs));
            bf16x8 k1 = *(const bf16x8*)(KsW + n*256 + (((1*4+gL)*16) ^ rs));
            bf16x8 k2 = *(const bf16x8*)(KsW + n*256 + (((2*4+gL)*16) ^ rs));
            bf16x8 k3 = *(const bf16x8*)(KsW + n*256 + (((3*4+gL)*16) ^ rs));
            #pragma unroll
            for (int mt = 0; mt < 2; mt++) {
                sacc[mt][nt] = __builtin_amdgcn_mfma_f32_16x16x32_bf16(qfrag[mt][0], k0, sacc[mt][nt], 0,0,0);
                sacc[mt][nt] = __builtin_amdgcn_mfma_f32_16x16x32_bf16(qfrag[mt][1], k1, sacc[mt][nt], 0,0,0);
                sacc[mt][nt] = __builtin_amdgcn_mfma_f32_16x16x32_bf16(qfrag[mt][2], k2, sacc[mt][nt], 0,0,0);
                sacc[mt][nt] = __builtin_amdgcn_mfma_f32_16x16x32_bf16(qfrag[mt][3], k3, sacc[mt][nt], 0,0,0);
            }
        }

        unsigned short* arow = (unsigned short*)AshW;
        #pragma unroll
        for (int nt = 0; nt < 4; nt++) {
            f32x4 cav = *(const f32x4*)(caSW + (nt*16 + cL)*16);
            #pragma unroll
            for (int mt = 0; mt < 2; mt++) {
                f32x4 s4 = sacc[mt][nt];
                float av[4];
                #pragma unroll
                for (int j = 0; j < 4; j++) {
                    float a = __expf(fminf(s4[j], 75.f)) * cav[3] * mq[mt][j];
                    if (!(a < 3.0e38f)) a = 0.f;
                    av[j] = a;
                    den[mt][j] += a;
                    axv[mt][j] += a * cav[0];
                    ayv[mt][j] += a * cav[1];
                    azv[mt][j] += a * cav[2];
                }
                unsigned int p01, p23;
                asm("v_cvt_pk_bf16_f32 %0, %1, %2" : "=v"(p01) : "v"(av[0]), "v"(av[1]));
                asm("v_cvt_pk_bf16_f32 %0, %1, %2" : "=v"(p23) : "v"(av[2]), "v"(av[3]));
                int qr = mt*16 + gL*4;
                int col = nt*16 + cL;
                arow[(qr+0)*72 + col] = (unsigned short)p01;
                arow[(qr+1)*72 + col] = (unsigned short)(p01 >> 16);
                arow[(qr+2)*72 + col] = (unsigned short)p23;
                arow[(qr+3)*72 + col] = (unsigned short)(p23 >> 16);
            }
        }

        #pragma unroll
        for (int ks = 0; ks < 2; ks++) {
            bf16x8 pa0 = *(const bf16x8*)(AshW + ((size_t)(cL)*72      + ks*32 + gL*8)*2);
            bf16x8 pa1 = *(const bf16x8*)(AshW + ((size_t)(16 + cL)*72 + ks*32 + gL*8)*2);
            #pragma unroll
            for (int dt = 0; dt < 8; dt++) {
                int d = dt*16 + cL;
                bf16x8 vb = *(const bf16x8*)(VtW + d*128 + (((ks*4+gL)*16) ^ ((d&7)<<4)));
                O[0][dt] = __builtin_amdgcn_mfma_f32_16x16x32_bf16(pa0, vb, O[0][dt], 0,0,0);
                O[1][dt] = __builtin_amdgcn_mfma_f32_16x16x32_bf16(pa1, vb, O[1][dt], 0,0,0);
            }
        }
    }

    __syncthreads();
    float* Ored = (float*)smem;            // [4][32][132]
    float* dred = (float*)(smem + 67584);  // [4][32][4]
    #pragma unroll
    for (int mt = 0; mt < 2; mt++)
        #pragma unroll
        for (int dt = 0; dt < 8; dt++) {
            f32x4 o4 = O[mt][dt];
            #pragma unroll
            for (int j = 0; j < 4; j++)
                Ored[w*4224 + (mt*16 + gL*4 + j)*132 + dt*16 + cL] = o4[j];
        }
    #pragma unroll
    for (int mt = 0; mt < 2; mt++)
        #pragma unroll
        for (int j = 0; j < 4; j++) {
            float d0 = den[mt][j], x0 = axv[mt][j], y0 = ayv[mt][j], z0 = azv[mt][j];
            #pragma unroll
            for (int off = 8; off >= 1; off >>= 1) {
                d0 += __shfl_xor(d0, off); x0 += __shfl_xor(x0, off);
                y0 += __shfl_xor(y0, off); z0 += __shfl_xor(z0, off);
            }
            if (cL == 0) {
                f32x4 v; v[0]=d0; v[1]=x0; v[2]=y0; v[3]=z0;
                *(f32x4*)&dred[w*128 + (mt*16 + gL*4 + j)*4] = v;
            }
        }
    __syncthreads();
    {
        int q = tid >> 3, d0 = (tid & 7) * 16;
        float dn = dred[q*4] + dred[128 + q*4] + dred[256 + q*4] + dred[384 + q*4];
        float inv = (dn > 0.f) ? 1.f/dn : 0.f;
        size_t rowb = (size_t)(qbase+q)*FA_LD + h*HD_ + d0;
        #pragma unroll
        for (int e = 0; e < 4; e++) {
            f32x4 s = *(const f32x4*)&Ored[q*132 + d0 + e*4];
            #pragma unroll
            for (int ww = 1; ww < 4; ww++)
                s += *(const f32x4*)&Ored[ww*4224 + q*132 + d0 + e*4];
            *(f32x4*)&fa[rowb + e*4] = s * inv;
        }
    }
    if (tid < 32) {
        float dn = dred[tid*4+0] + dred[128+tid*4+0] + dred[256+tid*4+0] + dred[384+tid*4+0];
        float ax = dred[tid*4+1] + dred[128+tid*4+1] + dred[256+tid*4+1] + dred[384+tid*4+1];
        float ay = dred[tid*4+2] + dred[128+tid*4+2] + dred[256+tid*4+2] + dred[384+tid*4+2];
        float az = dred[tid*4+3] + dred[128+tid*4+3] + dred[256+tid*4+3] + dred[384+tid*4+3];
        float inv = (dn > 0.f) ? 1.f/dn : 0.f;
        float live = (dn > 0.f) ? 1.f : 0.f;
        int qg = qbase + tid;
        float b0 = cb[qg*3+0]*live - ax*inv;
        float b1 = cb[qg*3+1]*live - ay*inv;
        float b2 = cb[qg*3+2]*live - az*inv;
        float dist = sqrtf(b0*b0 + b1*b1 + b2*b2);
        const float* F = fr + (size_t)qg*9;
        float p0 = F[0]*b0 + F[1]*b1 + F[2]*b2;
        float p1 = F[3]*b0 + F[4]*b1 + F[5]*b2;
        float p2 = F[6]*b0 + F[7]*b1 + F[8]*b2;
        float pn = sqrtf(p0*p0 + p1*p1 + p2*p2) + 1e-10f;
        size_t rb = (size_t)qg * FA_LD;
        fa[rb + 512 + h*3 + 0] = p0;
        fa[rb + 512 + h*3 + 1] = p1;
        fa[rb + 512 + h*3 + 2] = p2;
        fa[rb + 524 + h]       = dist;
        fa[rb + 528 + h*3 + 0] = p0/pn;
        fa[rb + 528 + h*3 + 1] = p1/pn;
        fa[rb + 528 + h*3 + 2] = p2/pn;
        if (h == 0) { fa[rb+540]=0.f; fa[rb+541]=0.f; fa[rb+542]=0.f; fa[rb+543]=0.f; }
    }
}

// ---------------------------------------------------------------- relu+LN1+mask+res+LN2 (R17 verbatim)
__global__ __launch_bounds__(256) void final_ln(
    const float* __restrict__ Y, const void* __restrict__ nf,
    const int* __restrict__ cai, const float* __restrict__ maskf,
    const void* __restrict__ g1, const void* __restrict__ b1,
    const void* __restrict__ g2, const void* __restrict__ b2,
    void* __restrict__ out, const int* __restrict__ flag)
{
    const int tid = threadIdx.x, lane = tid & 63, wave = tid >> 6;
    const int r = blockIdx.x * 4 + wave;
    bool f32 = *flag != 0;
    const float mk = maskf[r];
    const size_t xrow = (size_t)cai[r] * H_;
    float y[8], s1 = 0.f, s2 = 0.f;
    #pragma unroll
    for (int i = 0; i < 8; i++) {
        int c = lane + i*64;
        float v = fmaxf(Y[(size_t)r*H_ + c], 0.f);
        y[i] = v; s1 += v; s2 += v*v;
    }
    #pragma unroll
    for (int off = 32; off; off >>= 1) { s1 += __shfl_xor(s1, off); s2 += __shfl_xor(s2, off); }
    float mu = s1 * (1.f/H_);
    float var = s2 * (1.f/H_) - mu*mu;
    float rstd = rsqrtf(fmaxf(var, 0.f) + 1e-5f);
    float t[8], u1 = 0.f, u2 = 0.f;
    #pragma unroll
    for (int i = 0; i < 8; i++) {
        int c = lane + i*64;
        float hh = (y[i]-mu)*rstd*loadf(g1, c, f32) + loadf(b1, c, f32);
        hh *= mk;
        float tv = loadf(nf, xrow + c, f32) + hh;
        t[i] = tv; u1 += tv; u2 += tv*tv;
    }
    #pragma unroll
    for (int off = 32; off; off >>= 1) { u1 += __shfl_xor(u1, off); u2 += __shfl_xor(u2, off); }
    float mu2 = u1 * (1.f/H_);
    float var2 = u2 * (1.f/H_) - mu2*mu2;
    float rstd2 = rsqrtf(fmaxf(var2, 0.f) + 1e-5f);
    #pragma unroll
    for (int i = 0; i < 8; i++) {
        int c = lane + i*64;
        float ov = (t[i]-mu2)*rstd2*loadf(g2, c, f32) + loadf(b2, c, f32);
        if (f32) ((float*)out)[(size_t)r*H_ + c] = ov;
        else ((unsigned short*)out)[(size_t)r*H_ + c] = f2bf(ov);
    }
}

// ---------------------------------------------------------------- launch
extern "C" void kernel_launch(void* const* d_in, const int* in_sizes, int n_in,
                              void* d_out, int out_size, void* d_ws, size_t ws_size,
                              hipStream_t stream)
{
    static const int expected[16] = {
        8388608, 49152, 262144, 512, 262144, 512, 262144, 512,
        276480, 512, 512, 512, 512, 512, 16384, 16384
    };
    if (n_in != 16) {
        diag<<<dim3(1), dim3(64), 0, stream>>>((unsigned short*)d_out, 1000.f + n_in);
        return;
    }
    for (int i = 0; i < 16; i++) {
        if (in_sizes[i] != expected[i]) {
            diag<<<dim3(1), dim3(64), 0, stream>>>((unsigned short*)d_out, 2000.f + 10.f*i);
            return;
        }
    }
    const size_t need = 16056320;
    if (ws_size < need) {
        diag<<<dim3(1), dim3(64), 0, stream>>>((unsigned short*)d_out, 3000.f);
        return;
    }

    const void* nf  = d_in[0];
    const void* pos = d_in[1];
    const void* Wq  = d_in[2];  const void* bq = d_in[3];
    const void* Wk  = d_in[4];  const void* bk = d_in[5];
    const void* Wv  = d_in[6];  const void* bv = d_in[7];
    const void* Wo  = d_in[8];  const void* bo = d_in[9];
    const void* g1  = d_in[10]; const void* b1 = d_in[11];
    const void* g2  = d_in[12]; const void* b2 = d_in[13];
    const int* atype = (const int*)d_in[14];

    char* ws = (char*)d_ws;
    int*   flag  = (int*)  (ws + 0);
    int*   cai   = (int*)  (ws + 1024);
    float* ca    = (float*)(ws + 9216);
    float* cb    = (float*)(ws + 33792);
    float* fr    = (float*)(ws + 58368);
    float* maskf = (float*)(ws + 132096);
    unsigned short* qf = (unsigned short*)(ws + 1048576);
    unsigned short* kf = (unsigned short*)(ws + 3145728);
    unsigned short* vt = (unsigned short*)(ws + 5242880);   // [512][2048] bf16
    // xg planes alias the fa region (xg dead before attn writes fa)
    unsigned short* xg_hi = (unsigned short*)(ws + 7340032);
    unsigned short* xg_lo = (unsigned short*)(ws + 9437184);
    float* fa = (float*)(ws + 7340032);                     // [2048][544] f32
    unsigned short* wqt_hi = (unsigned short*)(ws + 11796480);
    unsigned short* wqt_lo = (unsigned short*)(ws + 13369344);
    unsigned short* wot_hi = (unsigned short*)(ws + 14942208);
    unsigned short* wot_lo = (unsigned short*)(ws + 15499264);
    float* Y  = (float*)qf;   // aliases qf+kf (4 MB) — both dead after attn

    detect_dtype<<<dim3(1), dim3(256), 0, stream>>>((const unsigned short*)nf, flag);
    gather_frames<<<dim3(8), dim3(256), 0, stream>>>(pos, atype, flag, cai, ca, cb, fr, maskf);
    pack_prep<<<dim3(2064), dim3(256), 0, stream>>>(nf, cai, Wq, Wk, Wv, Wo,
                                                    xg_hi, xg_lo, wqt_hi, wqt_lo,
                                                    wot_hi, wot_lo, flag);
    qkv_mfma<<<dim3(16, 12), dim3(256), 0, stream>>>(xg_hi, xg_lo, wqt_hi, wqt_lo,
                                                     bq, bk, bv, qf, kf, vt, flag);
    attn_mfma<<<dim3(R_/32, HEADS_), dim3(256), 0, stream>>>(qf, kf, vt,
                                                             ca, cb, fr, maskf, fa);
    wo_mfma<<<dim3(16, 4), dim3(256), 0, stream>>>(fa, wot_hi, wot_lo, bo, Y, flag);
    final_ln<<<dim3(512), dim3(256), 0, stream>>>(Y, nf, cai, maskf, g1, b1, g2, b2,
                                                  d_out, flag);
}